// Round 8
// baseline (4100.220 us; speedup 1.0000x reference)
//
#include <hip/hip_runtime.h>

#define NPTS   4096
#define NBATCH 4
#define KNN    16
#define DMODEL 512
#define DPOINT 128
#define QKVLD  1536              // row stride of fused q|k|v buffer

#define BM 128
#define BN 128
#define BK 64

typedef unsigned short bfu;                                     // bf16 bits
typedef __attribute__((ext_vector_type(8))) short short8;       // MFMA A/B frag
typedef __attribute__((ext_vector_type(4))) float f32x4;        // MFMA C/D frag

__device__ __forceinline__ bfu f2bf(float f) {                  // RNE f32->bf16
    unsigned u = __builtin_bit_cast(unsigned, f);
    return (bfu)((u + 0x7fffu + ((u >> 16) & 1u)) >> 16);
}
__device__ __forceinline__ float bf2f(bfu h) {
    unsigned u = ((unsigned)h) << 16;
    return __builtin_bit_cast(float, u);
}

__device__ __forceinline__ void gload_lds16(const bfu* g, bfu* l) {
    __builtin_amdgcn_global_load_lds(
        (const __attribute__((address_space(1))) void*)g,
        (__attribute__((address_space(3))) void*)l, 16, 0, 0);
}

// ---------------------------------------------------------------------------
// KNN v6: same algorithm as the proven r4/r7 kernel (8 threads/query,
// interleaved slices, register insertion sort, lex-(d,idx) bitonic merge) but
// occupancy-doubled: LDS tile halved to 2048 pts (32 KB, two staged passes)
// and VGPR capped at 128 via __launch_bounds__(256,4) -> 4 blocks/CU,
// 4 waves/SIMD. Distance unroll narrowed 8->4 to cut in-flight registers.
// Scan order per slice remains increasing m (half-major), distances are
// bit-identical, so the merged order equals jax top_k exactly as before.
// ---------------------------------------------------------------------------
#define TPQ  8                   // threads per query
#define QPB  32                  // queries per block (QPB*TPQ = 256)
#define HALF 2048                // points staged per pass (32 KB)

__device__ __forceinline__ void knn_merge_level(float* bd, int* bi, int lvl)
{
    float pd[KNN]; int pi[KNN];
#pragma unroll
    for (int i = 0; i < KNN; ++i) {              // partner's list, reversed
        pd[i] = __shfl_xor(bd[KNN-1-i], lvl);
        pi[i] = __shfl_xor(bi[KNN-1-i], lvl);
    }
#pragma unroll
    for (int i = 0; i < KNN; ++i) {              // lex-min -> lowest 16, bitonic
        bool take = (pd[i] < bd[i]) || (pd[i] == bd[i] && pi[i] < bi[i]);
        if (take) { bd[i] = pd[i]; bi[i] = pi[i]; }
    }
#pragma unroll
    for (int s = 8; s >= 1; s >>= 1) {           // bitonic merge network
#pragma unroll
        for (int i = 0; i < KNN; ++i) {
            if ((i & s) == 0) {
                const int j = i + s;
                bool sw = (bd[j] < bd[i]) || (bd[j] == bd[i] && bi[j] < bi[i]);
                if (sw) {
                    float td = bd[i]; bd[i] = bd[j]; bd[j] = td;
                    int   ti = bi[i]; bi[i] = bi[j]; bi[j] = ti;
                }
            }
        }
    }
}

__global__ __launch_bounds__(256, 4) void knn_kernel(const float* __restrict__ xyz,
                                                     int* __restrict__ knn_out)
{
    __shared__ float4 pts[HALF];   // 32 KB
    const int b    = blockIdx.y;
    const int tid  = threadIdx.x;
    const int qloc = tid >> 3;            // 0..31
    const int sub  = tid & 7;             // 0..7
    const int n    = blockIdx.x * QPB + qloc;

    const float* bx = xyz + (size_t)b * NPTS * 3;
    const float mex = bx[n*3+0], mey = bx[n*3+1], mez = bx[n*3+2];
    const float mew = mex*mex + mey*mey + mez*mez;

    float bd[KNN];
    int   bi[KNN];
#pragma unroll
    for (int i = 0; i < KNN; ++i) { bd[i] = 3.4e38f; bi[i] = -1; }

    for (int h = 0; h < NPTS / HALF; ++h) {
        __syncthreads();                  // previous pass fully scanned
        for (int i = tid; i < HALF; i += 256) {
            const int g = h * HALF + i;
            float x = bx[g*3+0], y = bx[g*3+1], z = bx[g*3+2];
            pts[i] = make_float4(x, y, z, x*x + y*y + z*z);
        }
        __syncthreads();

        // interleaved slice within the half: m_local = sub + 8*t
        for (int t0 = 0; t0 < HALF / TPQ; t0 += 4) {
            float d[4];
#pragma unroll
            for (int j = 0; j < 4; ++j) {
                float4 o = pts[sub + ((t0 + j) << 3)];
                d[j] = mew + o.w - 2.f*(mex*o.x + mey*o.y + mez*o.z);
            }
            float mn = fminf(fminf(d[0], d[1]), fminf(d[2], d[3]));
            if (mn < bd[KNN-1]) {
#pragma unroll
                for (int j = 0; j < 4; ++j) {
                    float dj = d[j];
                    if (dj < bd[KNN-1]) {
                        const int m = h * HALF + sub + ((t0 + j) << 3);
#pragma unroll
                        for (int i = KNN-1; i >= 1; --i) {
                            float dp = bd[i-1];
                            if (dp > dj)        { bd[i] = dp; bi[i] = bi[i-1]; }
                            else if (bd[i] > dj){ bd[i] = dj; bi[i] = m; }
                        }
                        if (bd[0] > dj) { bd[0] = dj; bi[0] = m; }
                    }
                }
            }
        }
    }

    // merge the 8 per-slice sorted lists (lanes sub^1, sub^2, sub^4)
    knn_merge_level(bd, bi, 1);
    knn_merge_level(bd, bi, 2);
    knn_merge_level(bd, bi, 4);

    // all 8 threads now hold the final sorted list; each writes 2 entries
    int* orow = knn_out + ((size_t)b*NPTS + n) * KNN;
    const int base = b * NPTS;
    orow[sub*2+0] = base + bi[sub*2+0];
    orow[sub*2+1] = base + bi[sub*2+1];
}

// ---------------------------------------------------------------------------
// f32 -> bf16 convert (vectorized) and transpose-convert for weights
// ---------------------------------------------------------------------------
__global__ __launch_bounds__(256) void cvt_bf16(const float* __restrict__ src,
                                                bfu* __restrict__ dst, int n4)
{
    int i = blockIdx.x * 256 + threadIdx.x;
    if (i < n4) {
        float4 v = ((const float4*)src)[i];
        bfu* d = dst + (size_t)i * 4;
        d[0] = f2bf(v.x); d[1] = f2bf(v.y); d[2] = f2bf(v.z); d[3] = f2bf(v.w);
    }
}

__global__ __launch_bounds__(256) void transpose_cvt(const float* __restrict__ src,
                                                     bfu* __restrict__ dst,
                                                     int K, int N)
{   // dst[n*K + k] = bf16(src[k*N + n])
    int i = blockIdx.x * 256 + threadIdx.x;
    if (i < K * N) {
        int n = i / K, k = i - n * K;
        dst[i] = f2bf(src[(size_t)k * N + n]);
    }
}

// ---------------------------------------------------------------------------
// MFMA GEMM, m97 structure: 128x128 tile, BK=64, 4 waves (2x2 of 64x64),
// 16x16x32 bf16 MFMA, global_load_lds width 16, 2 barriers per K-step.
// A [M][K] bf16 row-major (or fused on-the-fly source), BT [N][K] bf16.
// ASRC: 0 = plain A, 1 = pos_h = relu(rel @ d1 + b1) (d1 staged in LDS),
//       2 = q - k_gather + pos   (q/k live in the fused QKVLD-stride buffer).
// SMAX: fused scale+softmax(over 16 neighbor rows)+attn write(f32)+res reduce
//       (v also lives in the QKVLD-stride buffer).
// ---------------------------------------------------------------------------
template<int ASRC, bool BIAS, bool RELU, bool OUTBF, bool RESID, bool SMAX>
__global__ __launch_bounds__(256) void gemm_mfma(
    const bfu* __restrict__ A, const bfu* __restrict__ BT,
    const float* __restrict__ bias, const float* __restrict__ resid,
    void* __restrict__ Cout, int M, int Kd, int Nd,
    const float* __restrict__ xyz, const int* __restrict__ knng,
    const float* __restrict__ d1w, const float* __restrict__ d1b,
    const bfu* __restrict__ qb, const bfu* __restrict__ kb,
    const bfu* __restrict__ posc, const bfu* __restrict__ vb,
    bfu* __restrict__ resbuf, int row_base)
{
    __shared__ bfu As[BM * BK];
    __shared__ bfu Bs[BN * BK];

    const int tid  = threadIdx.x;
    const int lane = tid & 63;
    const int w    = tid >> 6;
    const int bm   = blockIdx.x * BM;
    const int bn   = blockIdx.y * BN;
    const int wm   = (w >> 1) * 64;
    const int wn   = (w & 1) * 64;
    const int lrow = lane & 15;
    const int kgrp = lane >> 4;

    f32x4 acc[4][4];
#pragma unroll
    for (int m = 0; m < 4; ++m)
#pragma unroll
        for (int n = 0; n < 4; ++n) acc[m][n] = (f32x4){0.f, 0.f, 0.f, 0.f};

    // fused-A row data (constant across K-steps)
    int   grow = 0, gnb = 0;
    float rx = 0.f, ry = 0.f, rz = 0.f;
    if constexpr (ASRC != 0) {
        int r = tid >> 1;
        grow  = row_base + bm + r;
        gnb   = knng[grow];
        if constexpr (ASRC == 1) {
            int p = grow >> 4;   // KNN = 16 rows per point
            rx = xyz[(size_t)p*3+0] - xyz[(size_t)gnb*3+0];
            ry = xyz[(size_t)p*3+1] - xyz[(size_t)gnb*3+1];
            rz = xyz[(size_t)p*3+2] - xyz[(size_t)gnb*3+2];
        }
    }

    // d1 weights staged to LDS once (ASRC==1 only)
    __shared__ float d1s[(ASRC == 1) ? 4 * DMODEL : 1];
    if constexpr (ASRC == 1) {
        for (int i = tid; i < DMODEL; i += 256) d1s[i] = d1b[i];
        for (int i = tid; i < 3 * DMODEL; i += 256) d1s[DMODEL + i] = d1w[i];
        // first __syncthreads() inside the K-loop publishes this
    }

    for (int k0 = 0; k0 < Kd; k0 += BK) {
        __syncthreads();   // previous tile fully consumed (+ d1s ready)

        // ---- stage B (always global_load_lds)
        {
            int r0 = w * 32;
            const bfu* gB = BT + (size_t)(bn + r0 + (lane >> 3)) * Kd + k0 + (lane & 7) * 8;
            bfu* lB = Bs + r0 * BK;
#pragma unroll
            for (int i = 0; i < 4; ++i)
                gload_lds16(gB + (size_t)i * 8 * Kd, lB + i * 8 * BK);
        }

        // ---- stage A
        if constexpr (ASRC == 0) {
            int r0 = w * 32;
            const bfu* gA = A + (size_t)(bm + r0 + (lane >> 3)) * Kd + k0 + (lane & 7) * 8;
            bfu* lA = As + r0 * BK;
#pragma unroll
            for (int i = 0; i < 4; ++i)
                gload_lds16(gA + (size_t)i * 8 * Kd, lA + i * 8 * BK);
        } else if constexpr (ASRC == 1) {
            int r = tid >> 1, cseg = (tid & 1) * 32;
#pragma unroll
            for (int c8 = 0; c8 < 4; ++c8) {
                short8 ov;
#pragma unroll
                for (int h = 0; h < 2; ++h) {
                    int kk2 = k0 + cseg + c8 * 8 + h * 4;
                    float4 fb = *(const float4*)&d1s[kk2];
                    float4 fx = *(const float4*)&d1s[DMODEL   + kk2];
                    float4 fy = *(const float4*)&d1s[2*DMODEL + kk2];
                    float4 fz = *(const float4*)&d1s[3*DMODEL + kk2];
                    ov[h*4+0] = (short)f2bf(fmaxf(fmaf(rz,fz.x,fmaf(ry,fy.x,fmaf(rx,fx.x,fb.x))),0.f));
                    ov[h*4+1] = (short)f2bf(fmaxf(fmaf(rz,fz.y,fmaf(ry,fy.y,fmaf(rx,fx.y,fb.y))),0.f));
                    ov[h*4+2] = (short)f2bf(fmaxf(fmaf(rz,fz.z,fmaf(ry,fy.z,fmaf(rx,fx.z,fb.z))),0.f));
                    ov[h*4+3] = (short)f2bf(fmaxf(fmaf(rz,fz.w,fmaf(ry,fy.w,fmaf(rx,fx.w,fb.w))),0.f));
                }
                *(short8*)&As[r * BK + cseg + c8 * 8] = ov;
            }
        } else {   // ASRC == 2: attn_in = q[p] - k[g] + pos  (QKVLD-stride q/k)
            int r = tid >> 1, cseg = (tid & 1) * 32;
            int p = grow >> 4;
            const bfu* qrow = qb   + (size_t)p    * QKVLD + k0 + cseg;
            const bfu* krow = kb   + (size_t)gnb  * QKVLD + k0 + cseg;
            const bfu* prow = posc + (size_t)(bm + r) * DMODEL + k0 + cseg;
#pragma unroll
            for (int c8 = 0; c8 < 4; ++c8) {
                short8 qv = *(const short8*)(qrow + c8 * 8);
                short8 kv = *(const short8*)(krow + c8 * 8);
                short8 pv = *(const short8*)(prow + c8 * 8);
                short8 ov;
#pragma unroll
                for (int j = 0; j < 8; ++j) {
                    float v = bf2f((bfu)qv[j]) - bf2f((bfu)kv[j]) + bf2f((bfu)pv[j]);
                    ov[j] = (short)f2bf(v);
                }
                *(short8*)&As[r * BK + cseg + c8 * 8] = ov;
            }
        }

        __syncthreads();   // compiler drains vmcnt(0)+lgkmcnt before barrier

        // ---- compute
#pragma unroll
        for (int kk = 0; kk < BK; kk += 32) {
            short8 af[4], bfr[4];
#pragma unroll
            for (int m = 0; m < 4; ++m)
                af[m] = *(const short8*)&As[(wm + m * 16 + lrow) * BK + kk + kgrp * 8];
#pragma unroll
            for (int n = 0; n < 4; ++n)
                bfr[n] = *(const short8*)&Bs[(wn + n * 16 + lrow) * BK + kk + kgrp * 8];
#pragma unroll
            for (int m = 0; m < 4; ++m)
#pragma unroll
                for (int n = 0; n < 4; ++n)
                    acc[m][n] = __builtin_amdgcn_mfma_f32_16x16x32_bf16(
                        af[m], bfr[n], acc[m][n], 0, 0, 0);
        }
    }

    if constexpr (SMAX) {
        // logits -> softmax over the 16 neighbor rows of each point -> attn
        // (f32, to Cout) + res partial reduce (bf16, to resbuf).
        const float scale = 0.044194173824159216f;   // 1/sqrt(512)
#pragma unroll
        for (int m = 0; m < 4; ++m) {
            const int row0 = bm + wm + m * 16 + kgrp * 4;    // chunk-local
            const int ploc = (bm + wm + m * 16) >> 4;        // chunk-local point
            int gnb4[4];
#pragma unroll
            for (int r = 0; r < 4; ++r) gnb4[r] = knng[(size_t)row_base + row0 + r];
#pragma unroll
            for (int n = 0; n < 4; ++n) {
                const int col = bn + wn + n * 16 + lrow;
                const float bv = bias[col];
                float v0 = (acc[m][n][0] + bv) * scale;
                float v1 = (acc[m][n][1] + bv) * scale;
                float v2 = (acc[m][n][2] + bv) * scale;
                float v3 = (acc[m][n][3] + bv) * scale;
                float mx = fmaxf(fmaxf(v0, v1), fmaxf(v2, v3));
                mx = fmaxf(mx, __shfl_xor(mx, 16));
                mx = fmaxf(mx, __shfl_xor(mx, 32));
                float e0 = __expf(v0 - mx), e1 = __expf(v1 - mx);
                float e2 = __expf(v2 - mx), e3 = __expf(v3 - mx);
                float s = e0 + e1 + e2 + e3;
                s += __shfl_xor(s, 16);
                s += __shfl_xor(s, 32);
                const float inv = 1.f / s;
                float a0 = e0*inv, a1 = e1*inv, a2 = e2*inv, a3 = e3*inv;
                float* ao = (float*)Cout;
                ao[(size_t)(row0 + 0) * DMODEL + col] = a0;
                ao[(size_t)(row0 + 1) * DMODEL + col] = a1;
                ao[(size_t)(row0 + 2) * DMODEL + col] = a2;
                ao[(size_t)(row0 + 3) * DMODEL + col] = a3;
                float res = 0.f;
                res = fmaf(a0, bf2f(vb[(size_t)gnb4[0]*QKVLD + col]) + bf2f(posc[(size_t)(row0+0)*DMODEL + col]), res);
                res = fmaf(a1, bf2f(vb[(size_t)gnb4[1]*QKVLD + col]) + bf2f(posc[(size_t)(row0+1)*DMODEL + col]), res);
                res = fmaf(a2, bf2f(vb[(size_t)gnb4[2]*QKVLD + col]) + bf2f(posc[(size_t)(row0+2)*DMODEL + col]), res);
                res = fmaf(a3, bf2f(vb[(size_t)gnb4[3]*QKVLD + col]) + bf2f(posc[(size_t)(row0+3)*DMODEL + col]), res);
                res += __shfl_xor(res, 16);
                res += __shfl_xor(res, 32);
                if (kgrp == 0) {
                    const size_t pglob = (size_t)(row_base >> 4) + ploc;
                    resbuf[pglob * DMODEL + col] = f2bf(res);
                }
            }
        }
        return;
    }

    // ---- standard epilogue: C row = (lane>>4)*4 + reg, col = lane&15
#pragma unroll
    for (int m = 0; m < 4; ++m) {
#pragma unroll
        for (int n = 0; n < 4; ++n) {
            int col = bn + wn + n * 16 + lrow;
            float bv = BIAS ? bias[col] : 0.f;
#pragma unroll
            for (int r = 0; r < 4; ++r) {
                int row = bm + wm + m * 16 + kgrp * 4 + r;
                float v = acc[m][n][r] + bv;
                if (RESID) v += resid[(size_t)row * Nd + col];
                if (RELU)  v = fmaxf(v, 0.f);
                if (OUTBF) ((bfu*)Cout)[(size_t)row * Nd + col] = f2bf(v);
                else     ((float*)Cout)[(size_t)row * Nd + col] = v;
            }
        }
    }
}

// ---------------------------------------------------------------------------
extern "C" void kernel_launch(void* const* d_in, const int* in_sizes, int n_in,
                              void* d_out, int out_size, void* d_ws, size_t ws_size,
                              hipStream_t stream)
{
    const float* xyz      = (const float*)d_in[0];
    const float* features = (const float*)d_in[1];
    const float* fc1_w    = (const float*)d_in[2];
    const float* fc1_b    = (const float*)d_in[3];
    const float* fc2_w    = (const float*)d_in[4];
    const float* fc2_b    = (const float*)d_in[5];
    const float* wq       = (const float*)d_in[6];
    const float* wk       = (const float*)d_in[7];
    const float* wv       = (const float*)d_in[8];
    const float* d1_w     = (const float*)d_in[9];
    const float* d1_b     = (const float*)d_in[10];
    const float* d2_w     = (const float*)d_in[11];
    const float* d2_b     = (const float*)d_in[12];
    const float* g1_w     = (const float*)d_in[13];
    const float* g1_b     = (const float*)d_in[14];
    const float* g2_w     = (const float*)d_in[15];
    const float* g2_b     = (const float*)d_in[16];

    const size_t Mpts  = (size_t)NBATCH * NPTS;      // 16384
    const size_t Mrows = Mpts * KNN;                 // 262144
    float* out_res  = (float*)d_out;                 // [16384,128]
    float* out_attn = (float*)d_out + Mpts * DPOINT; // [16384,16,512] f32

    // ---- workspace layout
    size_t off = 0;
    auto ab = [&](size_t elems) { bfu* r = (bfu*)((char*)d_ws + off); off += elems * 2; return r; };
    bfu* fc1T  = ab((size_t)DMODEL * DPOINT);        // [512][128]
    bfu* qkvT  = ab((size_t)QKVLD * DMODEL);         // [1536][512] = wq^T|wk^T|wv^T
    bfu* d2T   = ab((size_t)DMODEL * DMODEL);
    bfu* g1T   = ab((size_t)DMODEL * DMODEL);
    bfu* g2T   = ab((size_t)DMODEL * DMODEL);
    bfu* fc2T  = ab((size_t)DPOINT * DMODEL);        // [128][512]
    bfu* featb = ab(Mpts * DPOINT);
    bfu* xb    = ab(Mpts * DMODEL);
    bfu* qkvb  = ab(Mpts * QKVLD);                   // [16384][1536] q|k|v
    bfu* resb  = ab(Mpts * DMODEL);
    int* knng  = (int*)((char*)d_ws + off); off += Mrows * 4;

    int nchunk = 32;
    {
        const int cands[6] = {1, 2, 4, 8, 16, 32};
        for (int i = 0; i < 6; ++i) {
            size_t need = off + 2ull * (Mrows / cands[i]) * DMODEL * 2;
            if (need <= ws_size) { nchunk = cands[i]; break; }
        }
    }
    const size_t Rc  = Mrows / nchunk;               // rows per chunk
    bfu* posc = ab(Rc * DMODEL);
    bfu* hc   = ab(Rc * DMODEL);

    // ---- KNN + conversions
    knn_kernel<<<dim3(NPTS/QPB, NBATCH), 256, 0, stream>>>(xyz, knng);

    transpose_cvt<<<dim3((DPOINT*DMODEL+255)/256), 256, 0, stream>>>(fc1_w, fc1T, DPOINT, DMODEL);
    transpose_cvt<<<dim3((DMODEL*DMODEL+255)/256), 256, 0, stream>>>(wq, qkvT,                 DMODEL, DMODEL);
    transpose_cvt<<<dim3((DMODEL*DMODEL+255)/256), 256, 0, stream>>>(wk, qkvT +   DMODEL*DMODEL, DMODEL, DMODEL);
    transpose_cvt<<<dim3((DMODEL*DMODEL+255)/256), 256, 0, stream>>>(wv, qkvT + 2*DMODEL*DMODEL, DMODEL, DMODEL);
    transpose_cvt<<<dim3((DMODEL*DMODEL+255)/256), 256, 0, stream>>>(d2_w, d2T, DMODEL, DMODEL);
    transpose_cvt<<<dim3((DMODEL*DMODEL+255)/256), 256, 0, stream>>>(g1_w, g1T, DMODEL, DMODEL);
    transpose_cvt<<<dim3((DMODEL*DMODEL+255)/256), 256, 0, stream>>>(g2_w, g2T, DMODEL, DMODEL);
    transpose_cvt<<<dim3((DMODEL*DPOINT+255)/256), 256, 0, stream>>>(fc2_w, fc2T, DMODEL, DPOINT);
    cvt_bf16<<<dim3((Mpts*DPOINT/4+255)/256), 256, 0, stream>>>(features, featb, (int)(Mpts*DPOINT/4));

#define GEMM_ARGS(Ap, Bp, biasp, residp, Cp, M_, K_, N_, rb) \
    (Ap), (Bp), (biasp), (residp), (Cp), (int)(M_), (int)(K_), (int)(N_), \
    xyz, knng, d1_w, d1_b, qkvb, qkvb + DMODEL, posc, qkvb + 2*DMODEL, resb, (int)(rb)

    // ---- stage B: x = feat @ fc1 + b ; qkv = x @ [wq|wk|wv]  (one GEMM)
    gemm_mfma<0, true,  false, true,  false, false><<<dim3(Mpts/BM, DMODEL/BN), 256, 0, stream>>>(
        GEMM_ARGS(featb, fc1T, fc1_b, nullptr, xb, Mpts, DPOINT, DMODEL, 0));
    gemm_mfma<0, false, false, true,  false, false><<<dim3(Mpts/BM, QKVLD/BN), 256, 0, stream>>>(
        GEMM_ARGS(xb, qkvT, nullptr, nullptr, qkvb, Mpts, DMODEL, QKVLD, 0));

    // ---- chunked per-neighbor pipeline
    for (int c = 0; c < nchunk; ++c) {
        const size_t rb = (size_t)c * Rc;
        float* attn_c = out_attn + rb * DMODEL;

        // pos = relu(rel@d1+b1) @ d2 + b2      (A fused on the fly, d1 in LDS)
        gemm_mfma<1, true, false, true, false, false><<<dim3(Rc/BM, DMODEL/BN), 256, 0, stream>>>(
            GEMM_ARGS(nullptr, d2T, d2_b, nullptr, posc, Rc, DMODEL, DMODEL, rb));
        // h = relu((q - k_g + pos) @ g1 + b1)  (A fused on the fly)
        gemm_mfma<2, true, true,  true, false, false><<<dim3(Rc/BM, DMODEL/BN), 256, 0, stream>>>(
            GEMM_ARGS(nullptr, g1T, g1_b, nullptr, hc, Rc, DMODEL, DMODEL, rb));
        // logits = h @ g2 + b2 -> fused softmax + attn(f32) + res reduce
        gemm_mfma<0, false, false, false, false, true><<<dim3(Rc/BM, DMODEL/BN), 256, 0, stream>>>(
            GEMM_ARGS(hc, g2T, g2_b, nullptr, attn_c, Rc, DMODEL, DMODEL, rb));
    }

    // ---- out = res @ fc2 + b + features
    gemm_mfma<0, true, false, false, true, false><<<dim3(Mpts/BM, DPOINT/BN), 256, 0, stream>>>(
        GEMM_ARGS(resb, fc2T, fc2_b, features, out_res, Mpts, DMODEL, DPOINT, 0));
#undef GEMM_ARGS
}

// Round 9
// 2194.549 us; speedup vs baseline: 1.8684x; 1.8684x over previous
//
#include <hip/hip_runtime.h>

#define NPTS   4096
#define NBATCH 4
#define KNN    16
#define DMODEL 512
#define DPOINT 128
#define QKVLD  1536              // row stride of fused q|k|v buffer

#define BN 128
#define BK 64

typedef unsigned short bfu;                                     // bf16 bits
typedef __attribute__((ext_vector_type(8))) short short8;       // MFMA A/B frag
typedef __attribute__((ext_vector_type(4))) float f32x4;        // MFMA C/D frag

__device__ __forceinline__ bfu f2bf(float f) {                  // RNE f32->bf16
    unsigned u = __builtin_bit_cast(unsigned, f);
    return (bfu)((u + 0x7fffu + ((u >> 16) & 1u)) >> 16);
}
__device__ __forceinline__ float bf2f(bfu h) {
    unsigned u = ((unsigned)h) << 16;
    return __builtin_bit_cast(float, u);
}

__device__ __forceinline__ void gload_lds16(const bfu* g, bfu* l) {
    __builtin_amdgcn_global_load_lds(
        (const __attribute__((address_space(1))) void*)g,
        (__attribute__((address_space(3))) void*)l, 16, 0, 0);
}

// ---------------------------------------------------------------------------
// KNN — FROZEN r4/r7 version (measured 745 us, 0 bank conflicts, no spills).
// 8 threads/query, interleaved slices m = sub + 8*t, register insertion sort,
// 3-level shfl_xor bitonic merge under lex-(d,idx) = jax top_k order.
// Do NOT add launch_bounds caps: r6 (64/128) and r8 (256,4) both spilled the
// ~160-VGPR working set to scratch (WRITE_SIZE 2MB -> 12-15GB, 4x slower).
// ---------------------------------------------------------------------------
#define TPQ 8                    // threads per query
#define QPB 32                   // queries per block (QPB*TPQ = 256)

__device__ __forceinline__ void knn_merge_level(float* bd, int* bi, int lvl)
{
    float pd[KNN]; int pi[KNN];
#pragma unroll
    for (int i = 0; i < KNN; ++i) {              // partner's list, reversed
        pd[i] = __shfl_xor(bd[KNN-1-i], lvl);
        pi[i] = __shfl_xor(bi[KNN-1-i], lvl);
    }
#pragma unroll
    for (int i = 0; i < KNN; ++i) {              // lex-min -> lowest 16, bitonic
        bool take = (pd[i] < bd[i]) || (pd[i] == bd[i] && pi[i] < bi[i]);
        if (take) { bd[i] = pd[i]; bi[i] = pi[i]; }
    }
#pragma unroll
    for (int s = 8; s >= 1; s >>= 1) {           // bitonic merge network
#pragma unroll
        for (int i = 0; i < KNN; ++i) {
            if ((i & s) == 0) {
                const int j = i + s;
                bool sw = (bd[j] < bd[i]) || (bd[j] == bd[i] && bi[j] < bi[i]);
                if (sw) {
                    float td = bd[i]; bd[i] = bd[j]; bd[j] = td;
                    int   ti = bi[i]; bi[i] = bi[j]; bi[j] = ti;
                }
            }
        }
    }
}

__global__ __launch_bounds__(256) void knn_kernel(const float* __restrict__ xyz,
                                                  int* __restrict__ knn_out)
{
    __shared__ float4 pts[NPTS];   // 64 KB
    const int b    = blockIdx.y;
    const int tid  = threadIdx.x;
    const int qloc = tid >> 3;            // 0..31
    const int sub  = tid & 7;             // 0..7
    const int n    = blockIdx.x * QPB + qloc;

    const float* bx = xyz + (size_t)b * NPTS * 3;
    for (int i = tid; i < NPTS; i += 256) {
        float x = bx[i*3+0], y = bx[i*3+1], z = bx[i*3+2];
        pts[i] = make_float4(x, y, z, x*x + y*y + z*z);
    }
    __syncthreads();

    const float4 me = pts[n];
    float bd[KNN];
    int   bi[KNN];
#pragma unroll
    for (int i = 0; i < KNN; ++i) { bd[i] = 3.4e38f; bi[i] = -1; }

    // interleaved slice: m = sub + 8*t, t in [0, 512)
    for (int t0 = 0; t0 < NPTS / TPQ; t0 += 8) {
        float d[8];
#pragma unroll
        for (int j = 0; j < 8; ++j) {
            float4 o = pts[sub + ((t0 + j) << 3)];
            d[j] = me.w + o.w - 2.f*(me.x*o.x + me.y*o.y + me.z*o.z);
        }
        float mn = fminf(fminf(fminf(d[0],d[1]),fminf(d[2],d[3])),
                         fminf(fminf(d[4],d[5]),fminf(d[6],d[7])));
        if (mn < bd[KNN-1]) {
#pragma unroll
            for (int j = 0; j < 8; ++j) {
                float dj = d[j];
                if (dj < bd[KNN-1]) {
                    const int m = sub + ((t0 + j) << 3);
#pragma unroll
                    for (int i = KNN-1; i >= 1; --i) {
                        float dp = bd[i-1];
                        if (dp > dj)        { bd[i] = dp; bi[i] = bi[i-1]; }
                        else if (bd[i] > dj){ bd[i] = dj; bi[i] = m; }
                    }
                    if (bd[0] > dj) { bd[0] = dj; bi[0] = m; }
                }
            }
        }
    }

    // merge the 8 per-slice sorted lists (lanes sub^1, sub^2, sub^4)
    knn_merge_level(bd, bi, 1);
    knn_merge_level(bd, bi, 2);
    knn_merge_level(bd, bi, 4);

    // all 8 threads now hold the final sorted list; each writes 2 entries
    int* orow = knn_out + ((size_t)b*NPTS + n) * KNN;
    const int base = b * NPTS;
    orow[sub*2+0] = base + bi[sub*2+0];
    orow[sub*2+1] = base + bi[sub*2+1];
}

// ---------------------------------------------------------------------------
// f32 -> bf16 convert (vectorized) and transpose-convert for weights
// ---------------------------------------------------------------------------
__global__ __launch_bounds__(256) void cvt_bf16(const float* __restrict__ src,
                                                bfu* __restrict__ dst, int n4)
{
    int i = blockIdx.x * 256 + threadIdx.x;
    if (i < n4) {
        float4 v = ((const float4*)src)[i];
        bfu* d = dst + (size_t)i * 4;
        d[0] = f2bf(v.x); d[1] = f2bf(v.y); d[2] = f2bf(v.z); d[3] = f2bf(v.w);
    }
}

__global__ __launch_bounds__(256) void transpose_cvt(const float* __restrict__ src,
                                                     bfu* __restrict__ dst,
                                                     int K, int N)
{   // dst[n*K + k] = bf16(src[k*N + n])
    int i = blockIdx.x * 256 + threadIdx.x;
    if (i < K * N) {
        int n = i / K, k = i - n * K;
        dst[i] = f2bf(src[(size_t)k * N + n]);
    }
}

// ---------------------------------------------------------------------------
// pos_h = relu(rel @ d1_w + d1_b), materialized per chunk (memory-bound).
// One thread = 8 contiguous cols of one row; 64 threads per row.
// ---------------------------------------------------------------------------
__global__ __launch_bounds__(256) void pos_h_kernel(
    const float* __restrict__ xyz, const int* __restrict__ knng,
    const float* __restrict__ d1w, const float* __restrict__ d1b,
    bfu* __restrict__ out, int row_base)
{
    const int idx  = blockIdx.x * 256 + threadIdx.x;
    const int rloc = idx >> 6;                // chunk-local row
    const int c0   = (idx & 63) * 8;
    const int grow = row_base + rloc;
    const int p    = grow >> 4;
    const int nb   = knng[grow];
    const float rx = xyz[(size_t)p*3+0] - xyz[(size_t)nb*3+0];
    const float ry = xyz[(size_t)p*3+1] - xyz[(size_t)nb*3+1];
    const float rz = xyz[(size_t)p*3+2] - xyz[(size_t)nb*3+2];
    short8 ov;
#pragma unroll
    for (int j = 0; j < 8; ++j) {
        const int k = c0 + j;
        float v = d1b[k];
        v = fmaf(rx, d1w[k],        v);
        v = fmaf(ry, d1w[512 + k],  v);
        v = fmaf(rz, d1w[1024 + k], v);
        ov[j] = (short)f2bf(fmaxf(v, 0.f));
    }
    *(short8*)&out[(size_t)rloc * DMODEL + c0] = ov;
}

// ---------------------------------------------------------------------------
// MFMA GEMM, m97 structure, BMt x 128 tile (BMt = 128 or 64), BK=64, 4 waves,
// 16x16x32 bf16 MFMA, global_load_lds width 16, 2 barriers per K-step.
// ASRC: 0 = plain A [M][K] bf16; 2 = attn_in = q[p] - k[g] + pos (fused).
// SMAX: fused scale+softmax(16 neighbor rows)+attn write(f32)+res reduce.
// ---------------------------------------------------------------------------
template<int BMt, int ASRC, bool BIAS, bool RELU, bool OUTBF, bool RESID, bool SMAX>
__global__ __launch_bounds__(256) void gemm_mfma(
    const bfu* __restrict__ A, const bfu* __restrict__ BT,
    const float* __restrict__ bias, const float* __restrict__ resid,
    void* __restrict__ Cout, int M, int Kd, int Nd,
    const int* __restrict__ knng,
    const bfu* __restrict__ qb, const bfu* __restrict__ kb,
    const bfu* __restrict__ posc, const bfu* __restrict__ vb,
    bfu* __restrict__ resbuf, int row_base)
{
    constexpr int MF  = BMt / 32;     // m-fragments per wave (4 or 2)
    constexpr int TPR = 256 / BMt;    // threads per A-row in fused staging
    constexpr int RPW = BMt / 4;      // A rows staged per wave

    __shared__ bfu As[BMt * BK];
    __shared__ bfu Bs[BN * BK];

    const int tid  = threadIdx.x;
    const int lane = tid & 63;
    const int w    = tid >> 6;
    const int bm   = blockIdx.x * BMt;
    const int bn   = blockIdx.y * BN;
    const int wm   = (w >> 1) * (BMt / 2);
    const int wn   = (w & 1) * 64;
    const int lrow = lane & 15;
    const int kgrp = lane >> 4;

    f32x4 acc[MF][4];
#pragma unroll
    for (int m = 0; m < MF; ++m)
#pragma unroll
        for (int n = 0; n < 4; ++n) acc[m][n] = (f32x4){0.f, 0.f, 0.f, 0.f};

    int grow = 0, gnb = 0;
    if constexpr (ASRC == 2) {
        int r = tid / TPR;
        grow  = row_base + bm + r;
        gnb   = knng[grow];
    }

    for (int k0 = 0; k0 < Kd; k0 += BK) {
        __syncthreads();   // previous tile fully consumed

        // ---- stage B (always global_load_lds)
        {
            int r0 = w * 32;
            const bfu* gB = BT + (size_t)(bn + r0 + (lane >> 3)) * Kd + k0 + (lane & 7) * 8;
            bfu* lB = Bs + r0 * BK;
#pragma unroll
            for (int i = 0; i < 4; ++i)
                gload_lds16(gB + (size_t)i * 8 * Kd, lB + i * 8 * BK);
        }

        // ---- stage A
        if constexpr (ASRC == 0) {
            int r0 = w * RPW;
            const bfu* gA = A + (size_t)(bm + r0 + (lane >> 3)) * Kd + k0 + (lane & 7) * 8;
            bfu* lA = As + r0 * BK;
#pragma unroll
            for (int i = 0; i < RPW / 8; ++i)
                gload_lds16(gA + (size_t)i * 8 * Kd, lA + i * 8 * BK);
        } else {   // ASRC == 2: attn_in = q[p] - k[g] + pos
            constexpr int NC8 = (BK / TPR) / 8;   // short8s per thread
            int r = tid / TPR, cseg = (tid % TPR) * (BK / TPR);
            int p = grow >> 4;
            const bfu* qrow = qb   + (size_t)p    * QKVLD + k0 + cseg;
            const bfu* krow = kb   + (size_t)gnb  * QKVLD + k0 + cseg;
            const bfu* prow = posc + (size_t)(bm + r) * DMODEL + k0 + cseg;
#pragma unroll
            for (int c8 = 0; c8 < NC8; ++c8) {
                short8 qv = *(const short8*)(qrow + c8 * 8);
                short8 kv = *(const short8*)(krow + c8 * 8);
                short8 pv = *(const short8*)(prow + c8 * 8);
                short8 ov;
#pragma unroll
                for (int j = 0; j < 8; ++j) {
                    float v = bf2f((bfu)qv[j]) - bf2f((bfu)kv[j]) + bf2f((bfu)pv[j]);
                    ov[j] = (short)f2bf(v);
                }
                *(short8*)&As[r * BK + cseg + c8 * 8] = ov;
            }
        }

        __syncthreads();

        // ---- compute
#pragma unroll
        for (int kk = 0; kk < BK; kk += 32) {
            short8 af[MF], bfr[4];
#pragma unroll
            for (int m = 0; m < MF; ++m)
                af[m] = *(const short8*)&As[(wm + m * 16 + lrow) * BK + kk + kgrp * 8];
#pragma unroll
            for (int n = 0; n < 4; ++n)
                bfr[n] = *(const short8*)&Bs[(wn + n * 16 + lrow) * BK + kk + kgrp * 8];
#pragma unroll
            for (int m = 0; m < MF; ++m)
#pragma unroll
                for (int n = 0; n < 4; ++n)
                    acc[m][n] = __builtin_amdgcn_mfma_f32_16x16x32_bf16(
                        af[m], bfr[n], acc[m][n], 0, 0, 0);
        }
    }

    if constexpr (SMAX) {
        // logits -> softmax over the 16 neighbor rows of each point -> attn
        // (f32, to Cout) + res partial reduce (bf16, to resbuf).
        const float scale = 0.044194173824159216f;   // 1/sqrt(512)
#pragma unroll
        for (int m = 0; m < MF; ++m) {
            const int row0 = bm + wm + m * 16 + kgrp * 4;    // chunk-local
            const int ploc = (bm + wm + m * 16) >> 4;        // chunk-local point
            int gnb4[4];
#pragma unroll
            for (int r = 0; r < 4; ++r) gnb4[r] = knng[(size_t)row_base + row0 + r];
#pragma unroll
            for (int n = 0; n < 4; ++n) {
                const int col = bn + wn + n * 16 + lrow;
                const float bv = bias[col];
                float v0 = (acc[m][n][0] + bv) * scale;
                float v1 = (acc[m][n][1] + bv) * scale;
                float v2 = (acc[m][n][2] + bv) * scale;
                float v3 = (acc[m][n][3] + bv) * scale;
                float mx = fmaxf(fmaxf(v0, v1), fmaxf(v2, v3));
                mx = fmaxf(mx, __shfl_xor(mx, 16));
                mx = fmaxf(mx, __shfl_xor(mx, 32));
                float e0 = __expf(v0 - mx), e1 = __expf(v1 - mx);
                float e2 = __expf(v2 - mx), e3 = __expf(v3 - mx);
                float s = e0 + e1 + e2 + e3;
                s += __shfl_xor(s, 16);
                s += __shfl_xor(s, 32);
                const float inv = 1.f / s;
                float a0 = e0*inv, a1 = e1*inv, a2 = e2*inv, a3 = e3*inv;
                float* ao = (float*)Cout;
                ao[(size_t)(row0 + 0) * DMODEL + col] = a0;
                ao[(size_t)(row0 + 1) * DMODEL + col] = a1;
                ao[(size_t)(row0 + 2) * DMODEL + col] = a2;
                ao[(size_t)(row0 + 3) * DMODEL + col] = a3;
                float res = 0.f;
                res = fmaf(a0, bf2f(vb[(size_t)gnb4[0]*QKVLD + col]) + bf2f(posc[(size_t)(row0+0)*DMODEL + col]), res);
                res = fmaf(a1, bf2f(vb[(size_t)gnb4[1]*QKVLD + col]) + bf2f(posc[(size_t)(row0+1)*DMODEL + col]), res);
                res = fmaf(a2, bf2f(vb[(size_t)gnb4[2]*QKVLD + col]) + bf2f(posc[(size_t)(row0+2)*DMODEL + col]), res);
                res = fmaf(a3, bf2f(vb[(size_t)gnb4[3]*QKVLD + col]) + bf2f(posc[(size_t)(row0+3)*DMODEL + col]), res);
                res += __shfl_xor(res, 16);
                res += __shfl_xor(res, 32);
                if (kgrp == 0) {
                    const size_t pglob = (size_t)(row_base >> 4) + ploc;
                    resbuf[pglob * DMODEL + col] = f2bf(res);
                }
            }
        }
        return;
    }

    // ---- standard epilogue: C row = (lane>>4)*4 + reg, col = lane&15
#pragma unroll
    for (int m = 0; m < MF; ++m) {
#pragma unroll
        for (int n = 0; n < 4; ++n) {
            int col = bn + wn + n * 16 + lrow;
            float bv = BIAS ? bias[col] : 0.f;
#pragma unroll
            for (int r = 0; r < 4; ++r) {
                int row = bm + wm + m * 16 + kgrp * 4 + r;
                float v = acc[m][n][r] + bv;
                if (RESID) v += resid[(size_t)row * Nd + col];
                if (RELU)  v = fmaxf(v, 0.f);
                if (OUTBF) ((bfu*)Cout)[(size_t)row * Nd + col] = f2bf(v);
                else     ((float*)Cout)[(size_t)row * Nd + col] = v;
            }
        }
    }
}

// ---------------------------------------------------------------------------
extern "C" void kernel_launch(void* const* d_in, const int* in_sizes, int n_in,
                              void* d_out, int out_size, void* d_ws, size_t ws_size,
                              hipStream_t stream)
{
    const float* xyz      = (const float*)d_in[0];
    const float* features = (const float*)d_in[1];
    const float* fc1_w    = (const float*)d_in[2];
    const float* fc1_b    = (const float*)d_in[3];
    const float* fc2_w    = (const float*)d_in[4];
    const float* fc2_b    = (const float*)d_in[5];
    const float* wq       = (const float*)d_in[6];
    const float* wk       = (const float*)d_in[7];
    const float* wv       = (const float*)d_in[8];
    const float* d1_w     = (const float*)d_in[9];
    const float* d1_b     = (const float*)d_in[10];
    const float* d2_w     = (const float*)d_in[11];
    const float* d2_b     = (const float*)d_in[12];
    const float* g1_w     = (const float*)d_in[13];
    const float* g1_b     = (const float*)d_in[14];
    const float* g2_w     = (const float*)d_in[15];
    const float* g2_b     = (const float*)d_in[16];

    const size_t Mpts  = (size_t)NBATCH * NPTS;      // 16384
    const size_t Mrows = Mpts * KNN;                 // 262144
    float* out_res  = (float*)d_out;                 // [16384,128]
    float* out_attn = (float*)d_out + Mpts * DPOINT; // [16384,16,512] f32

    // ---- workspace layout (resb aliases xb: xb dead after qkv GEMM)
    size_t off = 0;
    auto ab = [&](size_t elems) { bfu* r = (bfu*)((char*)d_ws + off); off += elems * 2; return r; };
    bfu* fc1T  = ab((size_t)DMODEL * DPOINT);        // [512][128]
    bfu* qkvT  = ab((size_t)QKVLD * DMODEL);         // [1536][512] = wq^T|wk^T|wv^T
    bfu* d2T   = ab((size_t)DMODEL * DMODEL);
    bfu* g1T   = ab((size_t)DMODEL * DMODEL);
    bfu* g2T   = ab((size_t)DMODEL * DMODEL);
    bfu* fc2T  = ab((size_t)DPOINT * DMODEL);        // [128][512]
    bfu* featb = ab(Mpts * DPOINT);
    bfu* xb    = ab(Mpts * DMODEL);                  // reused as resb
    bfu* qkvb  = ab(Mpts * QKVLD);                   // [16384][1536] q|k|v
    bfu* resb  = xb;
    int* knng  = (int*)((char*)d_ws + off); off += Mrows * 4;

    int nchunk = 32;
    {
        const int cands[6] = {1, 2, 4, 8, 16, 32};
        for (int i = 0; i < 6; ++i) {
            size_t need = off + 2ull * (Mrows / cands[i]) * DMODEL * 2;
            if (need <= ws_size) { nchunk = cands[i]; break; }
        }
    }
    const size_t Rc  = Mrows / nchunk;               // rows per chunk
    bfu* posc = ab(Rc * DMODEL);
    bfu* hc   = ab(Rc * DMODEL);

    // ---- KNN + conversions
    knn_kernel<<<dim3(NPTS/QPB, NBATCH), 256, 0, stream>>>(xyz, knng);

    transpose_cvt<<<dim3((DPOINT*DMODEL+255)/256), 256, 0, stream>>>(fc1_w, fc1T, DPOINT, DMODEL);
    transpose_cvt<<<dim3((DMODEL*DMODEL+255)/256), 256, 0, stream>>>(wq, qkvT,                 DMODEL, DMODEL);
    transpose_cvt<<<dim3((DMODEL*DMODEL+255)/256), 256, 0, stream>>>(wk, qkvT +   DMODEL*DMODEL, DMODEL, DMODEL);
    transpose_cvt<<<dim3((DMODEL*DMODEL+255)/256), 256, 0, stream>>>(wv, qkvT + 2*DMODEL*DMODEL, DMODEL, DMODEL);
    transpose_cvt<<<dim3((DMODEL*DMODEL+255)/256), 256, 0, stream>>>(d2_w, d2T, DMODEL, DMODEL);
    transpose_cvt<<<dim3((DMODEL*DMODEL+255)/256), 256, 0, stream>>>(g1_w, g1T, DMODEL, DMODEL);
    transpose_cvt<<<dim3((DMODEL*DMODEL+255)/256), 256, 0, stream>>>(g2_w, g2T, DMODEL, DMODEL);
    transpose_cvt<<<dim3((DMODEL*DPOINT+255)/256), 256, 0, stream>>>(fc2_w, fc2T, DMODEL, DPOINT);
    cvt_bf16<<<dim3((Mpts*DPOINT/4+255)/256), 256, 0, stream>>>(features, featb, (int)(Mpts*DPOINT/4));

#define GARGS(Ap, Bp, biasp, residp, Cp, M_, K_, N_, rb) \
    (Ap), (Bp), (biasp), (residp), (Cp), (int)(M_), (int)(K_), (int)(N_), \
    knng, qkvb, qkvb + DMODEL, posc, qkvb + 2*DMODEL, resb, (int)(rb)

    // ---- stage B: x = feat @ fc1 + b ; qkv = x @ [wq|wk|wv]  (one GEMM)
    gemm_mfma<128, 0, true,  false, true,  false, false><<<dim3(Mpts/128, DMODEL/BN), 256, 0, stream>>>(
        GARGS(featb, fc1T, fc1_b, nullptr, xb, Mpts, DPOINT, DMODEL, 0));
    gemm_mfma<128, 0, false, false, true,  false, false><<<dim3(Mpts/128, QKVLD/BN), 256, 0, stream>>>(
        GARGS(xb, qkvT, nullptr, nullptr, qkvb, Mpts, DMODEL, QKVLD, 0));

    // ---- chunked per-neighbor pipeline
    for (int c = 0; c < nchunk; ++c) {
        const size_t rb = (size_t)c * Rc;
        float* attn_c = out_attn + rb * DMODEL;

        // pos_h = relu(rel@d1+b1) materialized into hc (memory-bound)
        pos_h_kernel<<<dim3((unsigned)(Rc/4)), 256, 0, stream>>>(xyz, knng, d1_w, d1_b, hc, (int)rb);

#define CHUNK_LAUNCH(BMT) \
        gemm_mfma<BMT, 0, true, false, true, false, false><<<dim3(Rc/BMT, DMODEL/BN), 256, 0, stream>>>( \
            GARGS(hc, d2T, d2_b, nullptr, posc, Rc, DMODEL, DMODEL, rb)); \
        gemm_mfma<BMT, 2, true, true,  true, false, false><<<dim3(Rc/BMT, DMODEL/BN), 256, 0, stream>>>( \
            GARGS(nullptr, g1T, g1_b, nullptr, hc, Rc, DMODEL, DMODEL, rb)); \
        gemm_mfma<BMT, 0, false, false, false, false, true><<<dim3(Rc/BMT, DMODEL/BN), 256, 0, stream>>>( \
            GARGS(hc, g2T, g2_b, nullptr, attn_c, Rc, DMODEL, DMODEL, rb));

        if (Rc >= 32768) { CHUNK_LAUNCH(128) }
        else             { CHUNK_LAUNCH(64)  }
#undef CHUNK_LAUNCH
    }

    // ---- out = res @ fc2 + b + features
    gemm_mfma<128, 0, true, false, false, true, false><<<dim3(Mpts/128, DPOINT/BN), 256, 0, stream>>>(
        GARGS(resb, fc2T, fc2_b, features, out_res, Mpts, DMODEL, DPOINT, 0));
#undef GARGS
}

// Round 10
// 1975.932 us; speedup vs baseline: 2.0751x; 1.1106x over previous
//
#include <hip/hip_runtime.h>

#define NPTS   4096
#define NBATCH 4
#define KNN    16
#define DMODEL 512
#define DPOINT 128
#define QKVLD  1536              // row stride of fused q|k|v buffer

#define BN 128
#define BK 64

typedef unsigned short bfu;                                     // bf16 bits
typedef __attribute__((ext_vector_type(8))) short short8;       // MFMA A/B frag
typedef __attribute__((ext_vector_type(4))) float f32x4;        // MFMA C/D frag

__device__ __forceinline__ bfu f2bf(float f) {                  // RNE f32->bf16
    unsigned u = __builtin_bit_cast(unsigned, f);
    return (bfu)((u + 0x7fffu + ((u >> 16) & 1u)) >> 16);
}
__device__ __forceinline__ float bf2f(bfu h) {
    unsigned u = ((unsigned)h) << 16;
    return __builtin_bit_cast(float, u);
}

__device__ __forceinline__ void gload_lds16(const bfu* g, bfu* l) {
    __builtin_amdgcn_global_load_lds(
        (const __attribute__((address_space(1))) void*)g,
        (__attribute__((address_space(3))) void*)l, 16, 0, 0);
}

// ---------------------------------------------------------------------------
// KNN — FROZEN r4/r7 version (measured 745 us, 0 bank conflicts, no spills).
// Do NOT add launch_bounds caps: r6/r8 both spilled the ~160-VGPR working set
// (WRITE_SIZE 2MB -> 12-15GB, 4x slower).
// ---------------------------------------------------------------------------
#define TPQ 8                    // threads per query
#define QPB 32                   // queries per block (QPB*TPQ = 256)

__device__ __forceinline__ void knn_merge_level(float* bd, int* bi, int lvl)
{
    float pd[KNN]; int pi[KNN];
#pragma unroll
    for (int i = 0; i < KNN; ++i) {              // partner's list, reversed
        pd[i] = __shfl_xor(bd[KNN-1-i], lvl);
        pi[i] = __shfl_xor(bi[KNN-1-i], lvl);
    }
#pragma unroll
    for (int i = 0; i < KNN; ++i) {              // lex-min -> lowest 16, bitonic
        bool take = (pd[i] < bd[i]) || (pd[i] == bd[i] && pi[i] < bi[i]);
        if (take) { bd[i] = pd[i]; bi[i] = pi[i]; }
    }
#pragma unroll
    for (int s = 8; s >= 1; s >>= 1) {           // bitonic merge network
#pragma unroll
        for (int i = 0; i < KNN; ++i) {
            if ((i & s) == 0) {
                const int j = i + s;
                bool sw = (bd[j] < bd[i]) || (bd[j] == bd[i] && bi[j] < bi[i]);
                if (sw) {
                    float td = bd[i]; bd[i] = bd[j]; bd[j] = td;
                    int   ti = bi[i]; bi[i] = bi[j]; bi[j] = ti;
                }
            }
        }
    }
}

__global__ __launch_bounds__(256) void knn_kernel(const float* __restrict__ xyz,
                                                  int* __restrict__ knn_out)
{
    __shared__ float4 pts[NPTS];   // 64 KB
    const int b    = blockIdx.y;
    const int tid  = threadIdx.x;
    const int qloc = tid >> 3;            // 0..31
    const int sub  = tid & 7;             // 0..7
    const int n    = blockIdx.x * QPB + qloc;

    const float* bx = xyz + (size_t)b * NPTS * 3;
    for (int i = tid; i < NPTS; i += 256) {
        float x = bx[i*3+0], y = bx[i*3+1], z = bx[i*3+2];
        pts[i] = make_float4(x, y, z, x*x + y*y + z*z);
    }
    __syncthreads();

    const float4 me = pts[n];
    float bd[KNN];
    int   bi[KNN];
#pragma unroll
    for (int i = 0; i < KNN; ++i) { bd[i] = 3.4e38f; bi[i] = -1; }

    // interleaved slice: m = sub + 8*t, t in [0, 512)
    for (int t0 = 0; t0 < NPTS / TPQ; t0 += 8) {
        float d[8];
#pragma unroll
        for (int j = 0; j < 8; ++j) {
            float4 o = pts[sub + ((t0 + j) << 3)];
            d[j] = me.w + o.w - 2.f*(me.x*o.x + me.y*o.y + me.z*o.z);
        }
        float mn = fminf(fminf(fminf(d[0],d[1]),fminf(d[2],d[3])),
                         fminf(fminf(d[4],d[5]),fminf(d[6],d[7])));
        if (mn < bd[KNN-1]) {
#pragma unroll
            for (int j = 0; j < 8; ++j) {
                float dj = d[j];
                if (dj < bd[KNN-1]) {
                    const int m = sub + ((t0 + j) << 3);
#pragma unroll
                    for (int i = KNN-1; i >= 1; --i) {
                        float dp = bd[i-1];
                        if (dp > dj)        { bd[i] = dp; bi[i] = bi[i-1]; }
                        else if (bd[i] > dj){ bd[i] = dj; bi[i] = m; }
                    }
                    if (bd[0] > dj) { bd[0] = dj; bi[0] = m; }
                }
            }
        }
    }

    // merge the 8 per-slice sorted lists (lanes sub^1, sub^2, sub^4)
    knn_merge_level(bd, bi, 1);
    knn_merge_level(bd, bi, 2);
    knn_merge_level(bd, bi, 4);

    // all 8 threads now hold the final sorted list; each writes 2 entries
    int* orow = knn_out + ((size_t)b*NPTS + n) * KNN;
    const int base = b * NPTS;
    orow[sub*2+0] = base + bi[sub*2+0];
    orow[sub*2+1] = base + bi[sub*2+1];
}

// ---------------------------------------------------------------------------
// f32 -> bf16 convert (vectorized) and transpose-convert for weights
// ---------------------------------------------------------------------------
__global__ __launch_bounds__(256) void cvt_bf16(const float* __restrict__ src,
                                                bfu* __restrict__ dst, int n4)
{
    int i = blockIdx.x * 256 + threadIdx.x;
    if (i < n4) {
        float4 v = ((const float4*)src)[i];
        bfu* d = dst + (size_t)i * 4;
        d[0] = f2bf(v.x); d[1] = f2bf(v.y); d[2] = f2bf(v.z); d[3] = f2bf(v.w);
    }
}

__global__ __launch_bounds__(256) void transpose_cvt(const float* __restrict__ src,
                                                     bfu* __restrict__ dst,
                                                     int K, int N)
{   // dst[n*K + k] = bf16(src[k*N + n])
    int i = blockIdx.x * 256 + threadIdx.x;
    if (i < K * N) {
        int n = i / K, k = i - n * K;
        dst[i] = f2bf(src[(size_t)k * N + n]);
    }
}

// ---------------------------------------------------------------------------
// pos_h = relu(rel @ d1_w + d1_b), materialized per chunk (memory-bound).
// ---------------------------------------------------------------------------
__global__ __launch_bounds__(256) void pos_h_kernel(
    const float* __restrict__ xyz, const int* __restrict__ knng,
    const float* __restrict__ d1w, const float* __restrict__ d1b,
    bfu* __restrict__ out, int row_base)
{
    const int idx  = blockIdx.x * 256 + threadIdx.x;
    const int rloc = idx >> 6;                // chunk-local row
    const int c0   = (idx & 63) * 8;
    const int grow = row_base + rloc;
    const int p    = grow >> 4;
    const int nb   = knng[grow];
    const float rx = xyz[(size_t)p*3+0] - xyz[(size_t)nb*3+0];
    const float ry = xyz[(size_t)p*3+1] - xyz[(size_t)nb*3+1];
    const float rz = xyz[(size_t)p*3+2] - xyz[(size_t)nb*3+2];
    short8 ov;
#pragma unroll
    for (int j = 0; j < 8; ++j) {
        const int k = c0 + j;
        float v = d1b[k];
        v = fmaf(rx, d1w[k],        v);
        v = fmaf(ry, d1w[512 + k],  v);
        v = fmaf(rz, d1w[1024 + k], v);
        ov[j] = (short)f2bf(fmaxf(v, 0.f));
    }
    *(short8*)&out[(size_t)rloc * DMODEL + c0] = ov;
}

// ---------------------------------------------------------------------------
// MFMA GEMM, m97 structure, BMt x 128 tile, BK=64, 4 waves, 16x16x32 bf16,
// global_load_lds width 16, 2 barriers per K-step.
// 1D grid + bijective XCD-chunk swizzle (nwg must be divisible by 8) +
// bn-fastest decomposition: within an XCD, consecutive logical blocks share
// the same A-tile -> A / posc / q / k re-reads become same-XCD L2 hits.
// ASRC: 0 = plain A [M][K] bf16; 2 = attn_in = q[p] - k[g] + pos (fused).
// SMAX: fused scale+softmax(16 neighbor rows)+attn write(f32)+res reduce.
// ---------------------------------------------------------------------------
template<int BMt, int ASRC, bool BIAS, bool RELU, bool OUTBF, bool RESID, bool SMAX>
__global__ __launch_bounds__(256) void gemm_mfma(
    const bfu* __restrict__ A, const bfu* __restrict__ BT,
    const float* __restrict__ bias, const float* __restrict__ resid,
    void* __restrict__ Cout, int M, int Kd, int Nd,
    const int* __restrict__ knng,
    const bfu* __restrict__ qb, const bfu* __restrict__ kb,
    const bfu* __restrict__ posc, const bfu* __restrict__ vb,
    bfu* __restrict__ resbuf, int row_base)
{
    constexpr int MF  = BMt / 32;     // m-fragments per wave (4 or 2)
    constexpr int TPR = 256 / BMt;    // threads per A-row in fused staging
    constexpr int RPW = BMt / 4;      // A rows staged per wave

    __shared__ bfu As[BMt * BK];
    __shared__ bfu Bs[BN * BK];

    const int tid  = threadIdx.x;
    const int lane = tid & 63;
    const int w    = tid >> 6;

    // XCD-chunk swizzle (bijective since gridDim.x % 8 == 0), bn fastest
    const int nbn     = Nd / BN;
    const int q8      = gridDim.x >> 3;
    const int logical = (blockIdx.x & 7) * q8 + (blockIdx.x >> 3);
    const int bm      = (logical / nbn) * BMt;
    const int bn      = (logical % nbn) * BN;

    const int wm   = (w >> 1) * (BMt / 2);
    const int wn   = (w & 1) * 64;
    const int lrow = lane & 15;
    const int kgrp = lane >> 4;

    f32x4 acc[MF][4];
#pragma unroll
    for (int m = 0; m < MF; ++m)
#pragma unroll
        for (int n = 0; n < 4; ++n) acc[m][n] = (f32x4){0.f, 0.f, 0.f, 0.f};

    int grow = 0, gnb = 0;
    if constexpr (ASRC == 2) {
        int r = tid / TPR;
        grow  = row_base + bm + r;
        gnb   = knng[grow];
    }

    for (int k0 = 0; k0 < Kd; k0 += BK) {
        __syncthreads();   // previous tile fully consumed

        // ---- stage B (always global_load_lds)
        {
            int r0 = w * 32;
            const bfu* gB = BT + (size_t)(bn + r0 + (lane >> 3)) * Kd + k0 + (lane & 7) * 8;
            bfu* lB = Bs + r0 * BK;
#pragma unroll
            for (int i = 0; i < 4; ++i)
                gload_lds16(gB + (size_t)i * 8 * Kd, lB + i * 8 * BK);
        }

        // ---- stage A
        if constexpr (ASRC == 0) {
            int r0 = w * RPW;
            const bfu* gA = A + (size_t)(bm + r0 + (lane >> 3)) * Kd + k0 + (lane & 7) * 8;
            bfu* lA = As + r0 * BK;
#pragma unroll
            for (int i = 0; i < RPW / 8; ++i)
                gload_lds16(gA + (size_t)i * 8 * Kd, lA + i * 8 * BK);
        } else {   // ASRC == 2: attn_in = q[p] - k[g] + pos
            constexpr int NC8 = (BK / TPR) / 8;   // short8s per thread
            int r = tid / TPR, cseg = (tid % TPR) * (BK / TPR);
            int p = grow >> 4;
            const bfu* qrow = qb   + (size_t)p    * QKVLD + k0 + cseg;
            const bfu* krow = kb   + (size_t)gnb  * QKVLD + k0 + cseg;
            const bfu* prow = posc + (size_t)(bm + r) * DMODEL + k0 + cseg;
#pragma unroll
            for (int c8 = 0; c8 < NC8; ++c8) {
                short8 qv = *(const short8*)(qrow + c8 * 8);
                short8 kv = *(const short8*)(krow + c8 * 8);
                short8 pv = *(const short8*)(prow + c8 * 8);
                short8 ov;
#pragma unroll
                for (int j = 0; j < 8; ++j) {
                    float v = bf2f((bfu)qv[j]) - bf2f((bfu)kv[j]) + bf2f((bfu)pv[j]);
                    ov[j] = (short)f2bf(v);
                }
                *(short8*)&As[r * BK + cseg + c8 * 8] = ov;
            }
        }

        __syncthreads();

        // ---- compute
#pragma unroll
        for (int kk = 0; kk < BK; kk += 32) {
            short8 af[MF], bfr[4];
#pragma unroll
            for (int m = 0; m < MF; ++m)
                af[m] = *(const short8*)&As[(wm + m * 16 + lrow) * BK + kk + kgrp * 8];
#pragma unroll
            for (int n = 0; n < 4; ++n)
                bfr[n] = *(const short8*)&Bs[(wn + n * 16 + lrow) * BK + kk + kgrp * 8];
#pragma unroll
            for (int m = 0; m < MF; ++m)
#pragma unroll
                for (int n = 0; n < 4; ++n)
                    acc[m][n] = __builtin_amdgcn_mfma_f32_16x16x32_bf16(
                        af[m], bfr[n], acc[m][n], 0, 0, 0);
        }
    }

    if constexpr (SMAX) {
        // logits -> softmax over the 16 neighbor rows of each point -> attn
        // (f32, to Cout) + res partial reduce (bf16, to resbuf).
        const float scale = 0.044194173824159216f;   // 1/sqrt(512)
#pragma unroll
        for (int m = 0; m < MF; ++m) {
            const int row0 = bm + wm + m * 16 + kgrp * 4;    // chunk-local
            const int ploc = (bm + wm + m * 16) >> 4;        // chunk-local point
            int gnb4[4];
#pragma unroll
            for (int r = 0; r < 4; ++r) gnb4[r] = knng[(size_t)row_base + row0 + r];
#pragma unroll
            for (int n = 0; n < 4; ++n) {
                const int col = bn + wn + n * 16 + lrow;
                const float bv = bias[col];
                float v0 = (acc[m][n][0] + bv) * scale;
                float v1 = (acc[m][n][1] + bv) * scale;
                float v2 = (acc[m][n][2] + bv) * scale;
                float v3 = (acc[m][n][3] + bv) * scale;
                float mx = fmaxf(fmaxf(v0, v1), fmaxf(v2, v3));
                mx = fmaxf(mx, __shfl_xor(mx, 16));
                mx = fmaxf(mx, __shfl_xor(mx, 32));
                float e0 = __expf(v0 - mx), e1 = __expf(v1 - mx);
                float e2 = __expf(v2 - mx), e3 = __expf(v3 - mx);
                float s = e0 + e1 + e2 + e3;
                s += __shfl_xor(s, 16);
                s += __shfl_xor(s, 32);
                const float inv = 1.f / s;
                float a0 = e0*inv, a1 = e1*inv, a2 = e2*inv, a3 = e3*inv;
                float* ao = (float*)Cout;
                ao[(size_t)(row0 + 0) * DMODEL + col] = a0;
                ao[(size_t)(row0 + 1) * DMODEL + col] = a1;
                ao[(size_t)(row0 + 2) * DMODEL + col] = a2;
                ao[(size_t)(row0 + 3) * DMODEL + col] = a3;
                float res = 0.f;
                res = fmaf(a0, bf2f(vb[(size_t)gnb4[0]*QKVLD + col]) + bf2f(posc[(size_t)(row0+0)*DMODEL + col]), res);
                res = fmaf(a1, bf2f(vb[(size_t)gnb4[1]*QKVLD + col]) + bf2f(posc[(size_t)(row0+1)*DMODEL + col]), res);
                res = fmaf(a2, bf2f(vb[(size_t)gnb4[2]*QKVLD + col]) + bf2f(posc[(size_t)(row0+2)*DMODEL + col]), res);
                res = fmaf(a3, bf2f(vb[(size_t)gnb4[3]*QKVLD + col]) + bf2f(posc[(size_t)(row0+3)*DMODEL + col]), res);
                res += __shfl_xor(res, 16);
                res += __shfl_xor(res, 32);
                if (kgrp == 0) {
                    const size_t pglob = (size_t)(row_base >> 4) + ploc;
                    resbuf[pglob * DMODEL + col] = f2bf(res);
                }
            }
        }
        return;
    }

    // ---- standard epilogue: C row = (lane>>4)*4 + reg, col = lane&15
#pragma unroll
    for (int m = 0; m < MF; ++m) {
#pragma unroll
        for (int n = 0; n < 4; ++n) {
            int col = bn + wn + n * 16 + lrow;
            float bv = BIAS ? bias[col] : 0.f;
#pragma unroll
            for (int r = 0; r < 4; ++r) {
                int row = bm + wm + m * 16 + kgrp * 4 + r;
                float v = acc[m][n][r] + bv;
                if (RESID) v += resid[(size_t)row * Nd + col];
                if (RELU)  v = fmaxf(v, 0.f);
                if (OUTBF) ((bfu*)Cout)[(size_t)row * Nd + col] = f2bf(v);
                else     ((float*)Cout)[(size_t)row * Nd + col] = v;
            }
        }
    }
}

// ---------------------------------------------------------------------------
extern "C" void kernel_launch(void* const* d_in, const int* in_sizes, int n_in,
                              void* d_out, int out_size, void* d_ws, size_t ws_size,
                              hipStream_t stream)
{
    const float* xyz      = (const float*)d_in[0];
    const float* features = (const float*)d_in[1];
    const float* fc1_w    = (const float*)d_in[2];
    const float* fc1_b    = (const float*)d_in[3];
    const float* fc2_w    = (const float*)d_in[4];
    const float* fc2_b    = (const float*)d_in[5];
    const float* wq       = (const float*)d_in[6];
    const float* wk       = (const float*)d_in[7];
    const float* wv       = (const float*)d_in[8];
    const float* d1_w     = (const float*)d_in[9];
    const float* d1_b     = (const float*)d_in[10];
    const float* d2_w     = (const float*)d_in[11];
    const float* d2_b     = (const float*)d_in[12];
    const float* g1_w     = (const float*)d_in[13];
    const float* g1_b     = (const float*)d_in[14];
    const float* g2_w     = (const float*)d_in[15];
    const float* g2_b     = (const float*)d_in[16];

    const size_t Mpts  = (size_t)NBATCH * NPTS;      // 16384
    const size_t Mrows = Mpts * KNN;                 // 262144
    float* out_res  = (float*)d_out;                 // [16384,128]
    float* out_attn = (float*)d_out + Mpts * DPOINT; // [16384,16,512] f32

    // ---- workspace layout (resb aliases xb: xb dead after qkv GEMM)
    size_t off = 0;
    auto ab = [&](size_t elems) { bfu* r = (bfu*)((char*)d_ws + off); off += elems * 2; return r; };
    bfu* fc1T  = ab((size_t)DMODEL * DPOINT);        // [512][128]
    bfu* qkvT  = ab((size_t)QKVLD * DMODEL);         // [1536][512] = wq^T|wk^T|wv^T
    bfu* d2T   = ab((size_t)DMODEL * DMODEL);
    bfu* g1T   = ab((size_t)DMODEL * DMODEL);
    bfu* g2T   = ab((size_t)DMODEL * DMODEL);
    bfu* fc2T  = ab((size_t)DPOINT * DMODEL);        // [128][512]
    bfu* featb = ab(Mpts * DPOINT);
    bfu* xb    = ab(Mpts * DMODEL);                  // reused as resb
    bfu* qkvb  = ab(Mpts * QKVLD);                   // [16384][1536] q|k|v
    bfu* resb  = xb;
    int* knng  = (int*)((char*)d_ws + off); off += Mrows * 4;

    // prefer nchunk=4: 64MB posc + 64MB hc -> both L3-resident, grid still full
    int nchunk = 32;
    {
        const int cands[4] = {4, 8, 16, 32};
        for (int i = 0; i < 4; ++i) {
            size_t need = off + 2ull * (Mrows / cands[i]) * DMODEL * 2;
            if (need <= ws_size) { nchunk = cands[i]; break; }
        }
    }
    const size_t Rc  = Mrows / nchunk;               // rows per chunk
    bfu* posc = ab(Rc * DMODEL);
    bfu* hc   = ab(Rc * DMODEL);

    // ---- KNN + conversions
    knn_kernel<<<dim3(NPTS/QPB, NBATCH), 256, 0, stream>>>(xyz, knng);

    transpose_cvt<<<dim3((DPOINT*DMODEL+255)/256), 256, 0, stream>>>(fc1_w, fc1T, DPOINT, DMODEL);
    transpose_cvt<<<dim3((DMODEL*DMODEL+255)/256), 256, 0, stream>>>(wq, qkvT,                 DMODEL, DMODEL);
    transpose_cvt<<<dim3((DMODEL*DMODEL+255)/256), 256, 0, stream>>>(wk, qkvT +   DMODEL*DMODEL, DMODEL, DMODEL);
    transpose_cvt<<<dim3((DMODEL*DMODEL+255)/256), 256, 0, stream>>>(wv, qkvT + 2*DMODEL*DMODEL, DMODEL, DMODEL);
    transpose_cvt<<<dim3((DMODEL*DMODEL+255)/256), 256, 0, stream>>>(d2_w, d2T, DMODEL, DMODEL);
    transpose_cvt<<<dim3((DMODEL*DMODEL+255)/256), 256, 0, stream>>>(g1_w, g1T, DMODEL, DMODEL);
    transpose_cvt<<<dim3((DMODEL*DMODEL+255)/256), 256, 0, stream>>>(g2_w, g2T, DMODEL, DMODEL);
    transpose_cvt<<<dim3((DMODEL*DPOINT+255)/256), 256, 0, stream>>>(fc2_w, fc2T, DMODEL, DPOINT);
    cvt_bf16<<<dim3((Mpts*DPOINT/4+255)/256), 256, 0, stream>>>(features, featb, (int)(Mpts*DPOINT/4));

#define GARGS(Ap, Bp, biasp, residp, Cp, M_, K_, N_, rb) \
    (Ap), (Bp), (biasp), (residp), (Cp), (int)(M_), (int)(K_), (int)(N_), \
    knng, qkvb, qkvb + DMODEL, posc, qkvb + 2*DMODEL, resb, (int)(rb)

    // ---- stage B: x = feat @ fc1 + b ; qkv = x @ [wq|wk|wv]  (one GEMM)
    gemm_mfma<128, 0, true,  false, true,  false, false><<<dim3((Mpts/128)*(DMODEL/BN)), 256, 0, stream>>>(
        GARGS(featb, fc1T, fc1_b, nullptr, xb, Mpts, DPOINT, DMODEL, 0));
    gemm_mfma<128, 0, false, false, true,  false, false><<<dim3((Mpts/128)*(QKVLD/BN)), 256, 0, stream>>>(
        GARGS(xb, qkvT, nullptr, nullptr, qkvb, Mpts, DMODEL, QKVLD, 0));

    // ---- chunked per-neighbor pipeline
    for (int c = 0; c < nchunk; ++c) {
        const size_t rb = (size_t)c * Rc;
        float* attn_c = out_attn + rb * DMODEL;

        // pos_h = relu(rel@d1+b1) materialized into hc (memory-bound)
        pos_h_kernel<<<dim3((unsigned)(Rc/4)), 256, 0, stream>>>(xyz, knng, d1_w, d1_b, hc, (int)rb);

#define CHUNK_LAUNCH(BMT) \
        gemm_mfma<BMT, 0, true, false, true, false, false><<<dim3((unsigned)((Rc/BMT)*(DMODEL/BN))), 256, 0, stream>>>( \
            GARGS(hc, d2T, d2_b, nullptr, posc, Rc, DMODEL, DMODEL, rb)); \
        gemm_mfma<BMT, 2, true, true,  true, false, false><<<dim3((unsigned)((Rc/BMT)*(DMODEL/BN))), 256, 0, stream>>>( \
            GARGS(nullptr, g1T, g1_b, nullptr, hc, Rc, DMODEL, DMODEL, rb)); \
        gemm_mfma<BMT, 0, false, false, false, false, true><<<dim3((unsigned)((Rc/BMT)*(DMODEL/BN))), 256, 0, stream>>>( \
            GARGS(hc, g2T, g2_b, nullptr, attn_c, Rc, DMODEL, DMODEL, rb));

        if (Rc >= 32768) { CHUNK_LAUNCH(128) }
        else             { CHUNK_LAUNCH(64)  }
#undef CHUNK_LAUNCH
    }

    // ---- out = res @ fc2 + b + features
    gemm_mfma<128, 0, true, false, false, true, false><<<dim3((Mpts/128)*(DPOINT/BN)), 256, 0, stream>>>(
        GARGS(resb, fc2T, fc2_b, features, out_res, Mpts, DMODEL, DPOINT, 0));
#undef GARGS
}